// Round 14
// baseline (256.855 us; speedup 1.0000x reference)
//
#include <hip/hip_runtime.h>
#include <math.h>

#define CDIM 768
#define NHEADS 12
#define HDIM 64
#define BATCH 4
#define SEQ 2048
#define MTOT (BATCH*SEQ)     // 8192
#define NQKV (3*CDIM)        // 2304
#define QROWS 128            // Q rows per attention block
#define VTILE 4096           // u16 elements per fragmented V tile (2 blk * 4 jd * 64 lane * 8)

typedef __attribute__((ext_vector_type(8))) short bf16x8;
typedef __attribute__((ext_vector_type(4))) float f32x4;
typedef unsigned short u16;
typedef unsigned int u32;

// async global->LDS, 16B per lane. LDS dest must be wave-uniform base + lane*16
// (global source address is per-lane free-form).
#define ASYNC16(gsrc, ldst) \
  __builtin_amdgcn_global_load_lds((const __attribute__((address_space(1))) void*)(gsrc), \
                                   (__attribute__((address_space(3))) void*)(ldst), 16, 0, 0)

// RNE fp32->bf16 (finite inputs only)
__device__ inline u16 f2b(float x) {
    unsigned int u = __float_as_uint(x);
    return (u16)((u + 0x7fffu + ((u >> 16) & 1u)) >> 16);
}
// rounding-biased uint for pack: hi16(u+0x8000) = round-half-up-in-magnitude bf16
__device__ inline u32 prnd(float x) { return __float_as_uint(x) + 0x8000u; }

// ---------------------------------------------------------------------------
// Fused prologue: x cast (6144 blocks) + 4 weight casts (4*576) + bias concat (9)
// ---------------------------------------------------------------------------
#define XBLK (MTOT*CDIM/1024)        // 6144
#define WBLK (CDIM*CDIM/1024)        // 576
__global__ __launch_bounds__(256)
void prep_kern(const float* __restrict__ x,
               const float* __restrict__ Wq, const float* __restrict__ Wk,
               const float* __restrict__ Wv, const float* __restrict__ Wo,
               const float* __restrict__ bq, const float* __restrict__ bk,
               const float* __restrict__ bv,
               u16* __restrict__ xb, u16* __restrict__ wqkv, u16* __restrict__ wob,
               float* __restrict__ bcat)
{
    int bx = blockIdx.x, tid = threadIdx.x;
    if (bx < XBLK) {
        int i = (bx * 256 + tid) * 4;
        float4 v = *(const float4*)(x + i);
        ushort4 o;
        o.x = f2b(v.x); o.y = f2b(v.y); o.z = f2b(v.z); o.w = f2b(v.w);
        *(ushort4*)(xb + i) = o;
    } else if (bx < XBLK + 4*WBLK) {
        int z = (bx - XBLK) / WBLK;
        int blk = (bx - XBLK) % WBLK;
        const float* src = (z == 0) ? Wq : (z == 1) ? Wk : (z == 2) ? Wv : Wo;
        u16* dst = (z == 3) ? wob : wqkv + (size_t)z * CDIM * CDIM;
        int i = (blk * 256 + tid) * 4;
        float4 v = *(const float4*)(src + i);
        ushort4 o;
        o.x = f2b(v.x); o.y = f2b(v.y); o.z = f2b(v.z); o.w = f2b(v.w);
        *(ushort4*)(dst + i) = o;
    } else {
        int i = (bx - XBLK - 4*WBLK) * 256 + tid;
        if (i < CDIM) bcat[i] = bq[i];
        else if (i < 2*CDIM) bcat[i] = bk[i - CDIM];
        else if (i < 3*CDIM) bcat[i] = bv[i - 2*CDIM];
    }
}

// ---------------------------------------------------------------------------
// bf16 GEMM: Y[m,n] = (sum_k A[m,k]*B[n,k] + bias[n]) * (n<qn ? qscale : 1)
// 128x128 tile, BK=64, 4 waves (2x2 of 64x64), 16x16x32 MFMA.
// A: XOR-swizzled global_load_lds staging, DOUBLE-BUFFERED (proven best of
// the 2-phase family, rounds 5/6/9/10).
// B: fragments read DIRECTLY from global (NO LDS). Why (r13 re-audit): with
// both operands LDS-staged, the CU-shared LDS pipe moves 96KB/block-step
// (32 staged + 64 read back — each byte read by 2 waves) ~= 1000+ cyc vs
// ~310 cyc MFMA/SIMD -> LDS ~3x oversubscribed; this is why MfmaUtil pinned
// at ~17% and every schedule variant (dbuf/tri-buf/vmcnt/BK/256^2) was null
// or worse. B = weights (3.5/1.2 MB), L2-resident per XCD after the T1
// swizzle; direct 16B/lane row-chunk reads are the same proven pattern as
// attn's Q/V-direct loads (r4-r12). LDS/step 96->48KB, LDS footprint
// 64->32KB -> 3-5 blocks/CU (TLP, the r8-proven dominant mechanism).
// 256^2 verdict (r13): FETCH halved but 1 block/CU -> occupancy collapse,
// 76us. Reverted.
// XCD-aware block swizzle (T1): FETCH 70.6MB -> L2-local panels.
// VFRAG=1: tiles with n0>=1536 (the V columns of the QKV GEMM) are written
// as pre-packed PV fragments into Vt instead of rows into Y.
// Fragment layout (matched to 16x16x32 PV MFMA, semantic k within a 32-key
// block: k(quad,j) = j<4 ? 4*quad+j : 16+4*quad+(j-4)):
//   epilogue element (i,j',r): seq s64 = i*16+quad*4+r -> t=i>>1,
//   word wj = 4*(i&1)+r, fragment lane = quad*16 + l15, jd = j'.
//   Vt[(bh*32+kt)*VTILE + ((t*4+jd)*64 + lane)*8 + 4*(i&1) + r]
// ---------------------------------------------------------------------------
template<int OUTF32, int VFRAG>
__global__ __launch_bounds__(256)
void gemm_bf16(const u16* __restrict__ A, const u16* __restrict__ B,
               const float* __restrict__ bias, void* __restrict__ Y,
               u16* __restrict__ Vt,
               int N, int K, int qn, float qscale)
{
    __shared__ __align__(16) u16 As[2][128*64];
    const int tid = threadIdx.x;
    // ---- XCD swizzle: nwg % 8 == 0 for all launches (1152 / 384) ----
    const int nwg = gridDim.x * gridDim.y;
    const int fid = blockIdx.y * gridDim.x + blockIdx.x;
    const int swz = (fid & 7) * (nwg >> 3) + (fid >> 3);
    const int m0 = (swz / gridDim.x) * 128, n0 = (swz % gridDim.x) * 128;
    const int wid = tid >> 6, lane = tid & 63;
    const int wm = (wid & 1) * 64, wn = (wid >> 1) * 64;
    const int l15 = lane & 15, quad = lane >> 4;

    f32x4 acc[4][4];
    #pragma unroll
    for (int i = 0; i < 4; ++i)
        #pragma unroll
        for (int j = 0; j < 4; ++j)
            #pragma unroll
            for (int r = 0; r < 4; ++r) acc[i][j][r] = 0.f;

    // stage A tile only: 4 ASYNC16/thread, XOR-swizzled rows
    auto stage = [&](int buf, int t) {
        int k0 = t * 64;
        #pragma unroll
        for (int r = 0; r < 4; ++r) {
            int li = r*256 + tid;
            int row = li >> 3, c = li & 7;
            int gc = c ^ (row & 7);
            ASYNC16(A + (size_t)(m0 + row) * K + k0 + gc*8, &As[buf][li*8]);
        }
    };

    const int NT = K / 64;
    stage(0, 0);
    __syncthreads();                       // drains prologue asyncs

    for (int t = 0; t < NT; ++t) {
        const int bufc = t & 1;
        const int k0 = t * 64;
        if (t + 1 < NT) stage(bufc ^ 1, t + 1);   // overlap with MFMA below
        #pragma unroll
        for (int kk = 0; kk < 2; ++kk) {
            bf16x8 a[4], b[4];
            // B fragments direct from global: row n, 16B chunk at quad
            #pragma unroll
            for (int j = 0; j < 4; ++j)
                b[j] = *(const bf16x8*)(B + (size_t)(n0 + wn + j*16 + l15) * K
                                        + k0 + kk*32 + quad*8);
            #pragma unroll
            for (int i = 0; i < 4; ++i) {
                int m = wm + i*16 + l15;
                int ca = (kk*4 + quad) ^ (m & 7);
                a[i] = *(const bf16x8*)&As[bufc][m*64 + ca*8];
            }
            __builtin_amdgcn_s_setprio(1);
            #pragma unroll
            for (int i = 0; i < 4; ++i)
                #pragma unroll
                for (int j = 0; j < 4; ++j)
                    acc[i][j] = __builtin_amdgcn_mfma_f32_16x16x32_bf16(a[i], b[j], acc[i][j], 0, 0, 0);
            __builtin_amdgcn_s_setprio(0);
        }
        __syncthreads();   // drains next-tile A asyncs; protects buffer reuse
    }

    if (VFRAG && n0 >= 2*CDIM) {
        // ---- V tile: write PV 16x16x32 B-fragments straight to Vt ----
        #pragma unroll
        for (int i = 0; i < 4; ++i) {
            int gm = m0 + wm + i*16 + quad*4;      // seq base for r=0..3
            int bb = gm >> 11;                     // batch
            int kt = (gm & 2047) >> 6;             // 64-key tile
            int t  = i >> 1;                       // 32-key block within tile
            int wj = (i & 1) * 4;                  // word offset in fragment
            #pragma unroll
            for (int j = 0; j < 4; ++j) {
                int gn = n0 + wn + j*16 + l15;
                float bv = bias[gn];
                int d = gn - 2*CDIM;
                int h = d >> 6, jd = (d & 63) >> 4;  // jd == j
                int bh = bb * NHEADS + h;
                u32 p0 = prnd(acc[i][j][0] + bv);
                u32 p1 = prnd(acc[i][j][1] + bv);
                u32 p2 = prnd(acc[i][j][2] + bv);
                u32 p3 = prnd(acc[i][j][3] + bv);
                uint2 st;
                st.x = __builtin_amdgcn_perm(p1, p0, 0x07060302u);
                st.y = __builtin_amdgcn_perm(p3, p2, 0x07060302u);
                *(uint2*)(Vt + ((size_t)(bh*32 + kt))*VTILE
                             + (size_t)((t*4 + jd)*64 + lane)*8 + wj) = st;
            }
        }
    } else {
        #pragma unroll
        for (int i = 0; i < 4; ++i) {
            #pragma unroll
            for (int j = 0; j < 4; ++j) {
                int gn = n0 + wn + j*16 + l15;
                float bv = bias[gn];
                float sc = (gn < qn) ? qscale : 1.0f;
                #pragma unroll
                for (int r = 0; r < 4; ++r) {
                    int gm = m0 + wm + i*16 + quad*4 + r;
                    float v = (acc[i][j][r] + bv) * sc;
                    if (OUTF32) ((float*)Y)[(size_t)gm * N + gn] = v;
                    else        ((u16*)Y)[(size_t)gm * N + gn] = f2b(v);
                }
            }
        }
    }
}

// ---------------------------------------------------------------------------
// MFMA flash attention, PAIRED K-TILES (round-12 version, total-best 208.0).
// 83% issue-sum (MFMA 38 + VALU 45) = near this structure's bound; T15 and
// pair-barrier variants both failed to beat it — attn is frozen.
// S^T = K.Q^T, exp2 in-register, P packed prnd+v_perm into bf16x8 fragments
// matching the Vt layout -> full-rate 16x16x32 PV. Zero-C first S-half.
// V split: idx-0 half LDS, idx-1 direct-global. setprio (T5), XCD swz (T1).
// ---------------------------------------------------------------------------
__global__ __launch_bounds__(256, 3)
void attn_mfma(const u16* __restrict__ QK, const u16* __restrict__ Vt,
               u16* __restrict__ Oa)
{
    __shared__ __align__(16) u16 Ks[2][2][64*64];   // [pair][tile-in-pair]
    __shared__ __align__(16) u16 Vls[2][2][2048];

    const int tid = threadIdx.x;
    const int wid = tid >> 6, lane = tid & 63;
    const int l15 = lane & 15, quad = lane >> 4;
    const int fid = blockIdx.y * gridDim.x + blockIdx.x;
    const int swz = (fid & 7) * 96 + (fid >> 3);
    const int qt = swz & 15, bh = swz >> 4;
    const int b = bh / NHEADS, h = bh % NHEADS;

    const u16* Qg  = QK + ((size_t)(b*SEQ + qt*QROWS)) * NQKV + h*HDIM;
    const u16* Kg0 = QK + ((size_t)(b*SEQ)) * NQKV + CDIM + h*HDIM;
    const u16* Vg  = Vt + (size_t)bh * 32 * VTILE;

    auto stage2 = [&](int wp, int kt) {
        #pragma unroll
        for (int u = 0; u < 2; ++u) {
            #pragma unroll
            for (int r = 0; r < 2; ++r) {
                int li = r*256 + tid, row = li >> 3, c = li & 7, gc = c ^ (row & 7);
                ASYNC16(Kg0 + (size_t)((kt+u)*64 + row) * NQKV + gc*8, &Ks[wp][u][li*8]);
            }
            ASYNC16(Vg + (size_t)(kt+u) * VTILE + tid*8, &Vls[wp][u][tid*8]);
        }
    };

    stage2(0, 0);

    bf16x8 qf[2][2];
    #pragma unroll
    for (int mb = 0; mb < 2; ++mb)
        #pragma unroll
        for (int kk = 0; kk < 2; ++kk)
            qf[mb][kk] = *(const bf16x8*)(Qg + (size_t)(wid*32 + mb*16 + l15) * NQKV + kk*32 + quad*8);

    const bf16x8 ONES8 = { (short)0x3F80, (short)0x3F80, (short)0x3F80, (short)0x3F80,
                           (short)0x3F80, (short)0x3F80, (short)0x3F80, (short)0x3F80 };
    const f32x4 ZERO4 = { 0.f, 0.f, 0.f, 0.f };

    f32x4 o[2][4];
    #pragma unroll
    for (int mb = 0; mb < 2; ++mb)
        #pragma unroll
        for (int j = 0; j < 4; ++j)
            #pragma unroll
            for (int r = 0; r < 4; ++r) o[mb][j][r] = 0.f;
    f32x4 ll[2];
    #pragma unroll
    for (int mb = 0; mb < 2; ++mb)
        #pragma unroll
        for (int r = 0; r < 4; ++r) ll[mb][r] = 0.f;

    __syncthreads();

    auto body = [&](int kt, int rp, int u) {
        bf16x8 vf[2][4];
        #pragma unroll
        for (int jd = 0; jd < 4; ++jd) {
            vf[0][jd] = *(const bf16x8*)&Vls[rp][u][(size_t)(jd*64 + lane)*8];
            vf[1][jd] = *(const bf16x8*)(Vg + (size_t)kt * VTILE
                                         + (size_t)((4 + jd)*64 + lane)*8);
        }

        f32x4 s[2][4];
        __builtin_amdgcn_s_setprio(1);
        #pragma unroll
        for (int j = 0; j < 4; ++j) {
            int kr = j*16 + l15;
            int ck = quad ^ (kr & 7);
            bf16x8 ak = *(const bf16x8*)&Ks[rp][u][kr*64 + ck*8];
            #pragma unroll
            for (int mb = 0; mb < 2; ++mb)
                s[mb][j] = __builtin_amdgcn_mfma_f32_16x16x32_bf16(ak, qf[mb][0], ZERO4, 0, 0, 0);
        }
        #pragma unroll
        for (int j = 0; j < 4; ++j) {
            int kr = j*16 + l15;
            int ck = (4 + quad) ^ (kr & 7);
            bf16x8 ak = *(const bf16x8*)&Ks[rp][u][kr*64 + ck*8];
            #pragma unroll
            for (int mb = 0; mb < 2; ++mb)
                s[mb][j] = __builtin_amdgcn_mfma_f32_16x16x32_bf16(ak, qf[mb][1], s[mb][j], 0, 0, 0);
        }
        __builtin_amdgcn_s_setprio(0);

        bf16x8 pf[2][2];
        #pragma unroll
        for (int mb = 0; mb < 2; ++mb)
            #pragma unroll
            for (int t = 0; t < 2; ++t) {
                u32 a0 = prnd(__builtin_amdgcn_exp2f(s[mb][2*t][0]));
                u32 a1 = prnd(__builtin_amdgcn_exp2f(s[mb][2*t][1]));
                u32 a2 = prnd(__builtin_amdgcn_exp2f(s[mb][2*t][2]));
                u32 a3 = prnd(__builtin_amdgcn_exp2f(s[mb][2*t][3]));
                u32 b0 = prnd(__builtin_amdgcn_exp2f(s[mb][2*t+1][0]));
                u32 b1 = prnd(__builtin_amdgcn_exp2f(s[mb][2*t+1][1]));
                u32 b2 = prnd(__builtin_amdgcn_exp2f(s[mb][2*t+1][2]));
                u32 b3 = prnd(__builtin_amdgcn_exp2f(s[mb][2*t+1][3]));
                union { uint4 u; bf16x8 v; } cst;
                cst.u.x = __builtin_amdgcn_perm(a1, a0, 0x07060302u);
                cst.u.y = __builtin_amdgcn_perm(a3, a2, 0x07060302u);
                cst.u.z = __builtin_amdgcn_perm(b1, b0, 0x07060302u);
                cst.u.w = __builtin_amdgcn_perm(b3, b2, 0x07060302u);
                pf[mb][t] = cst.v;
            }

        __builtin_amdgcn_s_setprio(1);
        #pragma unroll
        for (int t = 0; t < 2; ++t) {
            #pragma unroll
            for (int jd = 0; jd < 4; ++jd) {
                #pragma unroll
                for (int mb = 0; mb < 2; ++mb)
                    o[mb][jd] = __builtin_amdgcn_mfma_f32_16x16x32_bf16(pf[mb][t], vf[t][jd], o[mb][jd], 0, 0, 0);
            }
            #pragma unroll
            for (int mb = 0; mb < 2; ++mb)
                ll[mb] = __builtin_amdgcn_mfma_f32_16x16x32_bf16(pf[mb][t], ONES8, ll[mb], 0, 0, 0);
        }
        __builtin_amdgcn_s_setprio(0);
    };

    for (int s = 0; s < 16; ++s) {
        const int rp = s & 1, wp = rp ^ 1;
        if (s < 15) stage2(wp, 2*s + 2);
        body(2*s,     rp, 0);
        body(2*s + 1, rp, 1);
        __syncthreads();
    }

    u16* Og = Oa + ((size_t)(b*SEQ + qt*QROWS)) * CDIM + h*HDIM;
    #pragma unroll
    for (int mb = 0; mb < 2; ++mb) {
        #pragma unroll
        for (int r = 0; r < 4; ++r) {
            float inv = 1.f / ll[mb][r];
            int row = wid*32 + mb*16 + quad*4 + r;
            #pragma unroll
            for (int jd = 0; jd < 4; ++jd)
                Og[(size_t)row * CDIM + jd*16 + l15] = f2b(o[mb][jd][r] * inv);
        }
    }
}

// ---------------------------------------------------------------------------
extern "C" void kernel_launch(void* const* d_in, const int* in_sizes, int n_in,
                              void* d_out, int out_size, void* d_ws, size_t ws_size,
                              hipStream_t stream)
{
    const float* x  = (const float*)d_in[0];
    const float* Wq = (const float*)d_in[1];
    const float* bq = (const float*)d_in[2];
    const float* Wk = (const float*)d_in[3];
    const float* bk = (const float*)d_in[4];
    const float* Wv = (const float*)d_in[5];
    const float* bv = (const float*)d_in[6];
    const float* Wo = (const float*)d_in[7];
    const float* bo = (const float*)d_in[8];

    unsigned char* ws = (unsigned char*)d_ws;
    u16* xb   = (u16*)ws;  ws += (size_t)MTOT * CDIM * 2;
    u16* wqkv = (u16*)ws;  ws += (size_t)NQKV * CDIM * 2;
    u16* wob  = (u16*)ws;  ws += (size_t)CDIM * CDIM * 2;
    float* bcat = (float*)ws; ws += (size_t)NQKV * 4;
    u16* qkv  = (u16*)ws;  ws += (size_t)MTOT * NQKV * 2;
    u16* vt   = (u16*)ws;  ws += (size_t)BATCH*NHEADS*32*VTILE * 2;
    u16* ao   = (u16*)ws;

    prep_kern<<<XBLK + 4*WBLK + 9, 256, 0, stream>>>(x, Wq, Wk, Wv, Wo, bq, bk, bv,
                                                     xb, wqkv, wob, bcat);

    // q pre-scaled by log2(e)/sqrt(HDIM) so softmax is a bare exp2
    gemm_bf16<0,1><<<dim3(NQKV/128, MTOT/128), 256, 0, stream>>>(xb, wqkv, bcat, qkv, vt, NQKV, CDIM, CDIM, 0.18033688f);
    attn_mfma<<<dim3(SEQ/QROWS, BATCH*NHEADS), 256, 0, stream>>>(qkv, vt, ao);
    gemm_bf16<1,0><<<dim3(CDIM/128, MTOT/128), 256, 0, stream>>>(ao, wob, bo, (float*)d_out, nullptr, CDIM, CDIM, 0, 1.0f);
}

// Round 15
// 251.599 us; speedup vs baseline: 1.0209x; 1.0209x over previous
//
#include <hip/hip_runtime.h>
#include <math.h>

#define CDIM 768
#define NHEADS 12
#define HDIM 64
#define BATCH 4
#define SEQ 2048
#define MTOT (BATCH*SEQ)     // 8192
#define NQKV (3*CDIM)        // 2304
#define QROWS 128            // Q rows per attention block
#define VTILE 4096           // u16 elements per fragmented V tile (2 blk * 4 jd * 64 lane * 8)

typedef __attribute__((ext_vector_type(8))) short bf16x8;
typedef __attribute__((ext_vector_type(4))) float f32x4;
typedef unsigned short u16;
typedef unsigned int u32;

// async global->LDS, 16B per lane. LDS dest must be wave-uniform base + lane*16
// (global source address is per-lane free-form).
#define ASYNC16(gsrc, ldst) \
  __builtin_amdgcn_global_load_lds((const __attribute__((address_space(1))) void*)(gsrc), \
                                   (__attribute__((address_space(3))) void*)(ldst), 16, 0, 0)

// RNE fp32->bf16 (finite inputs only)
__device__ inline u16 f2b(float x) {
    unsigned int u = __float_as_uint(x);
    return (u16)((u + 0x7fffu + ((u >> 16) & 1u)) >> 16);
}
// rounding-biased uint for pack: hi16(u+0x8000) = round-half-up-in-magnitude bf16
__device__ inline u32 prnd(float x) { return __float_as_uint(x) + 0x8000u; }

// ---------------------------------------------------------------------------
// Fused prologue: x cast (6144 blocks) + 4 weight casts (4*576) + bias concat (9)
// ---------------------------------------------------------------------------
#define XBLK (MTOT*CDIM/1024)        // 6144
#define WBLK (CDIM*CDIM/1024)        // 576
__global__ __launch_bounds__(256)
void prep_kern(const float* __restrict__ x,
               const float* __restrict__ Wq, const float* __restrict__ Wk,
               const float* __restrict__ Wv, const float* __restrict__ Wo,
               const float* __restrict__ bq, const float* __restrict__ bk,
               const float* __restrict__ bv,
               u16* __restrict__ xb, u16* __restrict__ wqkv, u16* __restrict__ wob,
               float* __restrict__ bcat)
{
    int bx = blockIdx.x, tid = threadIdx.x;
    if (bx < XBLK) {
        int i = (bx * 256 + tid) * 4;
        float4 v = *(const float4*)(x + i);
        ushort4 o;
        o.x = f2b(v.x); o.y = f2b(v.y); o.z = f2b(v.z); o.w = f2b(v.w);
        *(ushort4*)(xb + i) = o;
    } else if (bx < XBLK + 4*WBLK) {
        int z = (bx - XBLK) / WBLK;
        int blk = (bx - XBLK) % WBLK;
        const float* src = (z == 0) ? Wq : (z == 1) ? Wk : (z == 2) ? Wv : Wo;
        u16* dst = (z == 3) ? wob : wqkv + (size_t)z * CDIM * CDIM;
        int i = (blk * 256 + tid) * 4;
        float4 v = *(const float4*)(src + i);
        ushort4 o;
        o.x = f2b(v.x); o.y = f2b(v.y); o.z = f2b(v.z); o.w = f2b(v.w);
        *(ushort4*)(dst + i) = o;
    } else {
        int i = (bx - XBLK - 4*WBLK) * 256 + tid;
        if (i < CDIM) bcat[i] = bq[i];
        else if (i < 2*CDIM) bcat[i] = bk[i - CDIM];
        else if (i < 3*CDIM) bcat[i] = bv[i - 2*CDIM];
    }
}

// ---------------------------------------------------------------------------
// bf16 GEMM: Y[m,n] = (sum_k A[m,k]*B[n,k] + bias[n]) * (n<qn ? qscale : 1)
// 128x128 tile, BK=64, 4 waves (2x2 of 64x64), 16x16x32 MFMA.
// A: XOR-swizzled global_load_lds staging, DOUBLE-BUFFERED.
// B: REGISTER-PREFETCHED one full tile ahead, direct from global (no LDS).
// Why: LDS-pipe model fits measurements (both-LDS: 2 blk x 96KB/step /
// 128B/cyc ~= 1500 cyc vs 310 cyc MFMA -> predicted MfmaUtil ~21%, measured
// 17%) — LDS ~3x oversubscribed. r14's B-direct failed ONLY on exposed
// latency (loads issued right before use, MfmaUtil 12.7). Here b-loads for
// tile t+1 issue at the TOP of tile t (named b0/b1 states, t+=2 unroll,
// all indices compile-time) and drain at the end-of-tile barrier — a full
// tile (~600 cyc) of cover. Per-step LDS 96->48KB; B rides L1 (parallel
// pipe); LDS footprint 64->32KB -> ~3 blocks/CU.
// Family verdict so far: single-buf 65.9; BK=64 dbuf 58 (r12 best);
// BK=32 variants worse; 256^2 worse (occupancy collapse); B-direct-no-
// prefetch 87.
// XCD-aware block swizzle (T1).
// VFRAG=1: V-column tiles written as pre-packed PV fragments into Vt:
//   Vt[(bh*32+kt)*VTILE + ((t*4+jd)*64 + lane)*8 + 4*(i&1) + r]
// ---------------------------------------------------------------------------
template<int OUTF32, int VFRAG>
__global__ __launch_bounds__(256)
void gemm_bf16(const u16* __restrict__ A, const u16* __restrict__ B,
               const float* __restrict__ bias, void* __restrict__ Y,
               u16* __restrict__ Vt,
               int N, int K, int qn, float qscale)
{
    __shared__ __align__(16) u16 As[2][128*64];
    const int tid = threadIdx.x;
    // ---- XCD swizzle: nwg % 8 == 0 for all launches (1152 / 384) ----
    const int nwg = gridDim.x * gridDim.y;
    const int fid = blockIdx.y * gridDim.x + blockIdx.x;
    const int swz = (fid & 7) * (nwg >> 3) + (fid >> 3);
    const int m0 = (swz / gridDim.x) * 128, n0 = (swz % gridDim.x) * 128;
    const int wid = tid >> 6, lane = tid & 63;
    const int wm = (wid & 1) * 64, wn = (wid >> 1) * 64;
    const int l15 = lane & 15, quad = lane >> 4;

    f32x4 acc[4][4];
    #pragma unroll
    for (int i = 0; i < 4; ++i)
        #pragma unroll
        for (int j = 0; j < 4; ++j)
            #pragma unroll
            for (int r = 0; r < 4; ++r) acc[i][j][r] = 0.f;

    // stage A tile only: 4 ASYNC16/thread, XOR-swizzled rows
    auto stage = [&](int buf, int t) {
        int k0 = t * 64;
        #pragma unroll
        for (int r = 0; r < 4; ++r) {
            int li = r*256 + tid;
            int row = li >> 3, c = li & 7;
            int gc = c ^ (row & 7);
            ASYNC16(A + (size_t)(m0 + row) * K + k0 + gc*8, &As[buf][li*8]);
        }
    };

    // prefetch all 8 B fragments of tile t into registers
    auto loadB = [&](bf16x8 (&bb)[2][4], int t) {
        int k0 = t * 64;
        #pragma unroll
        for (int kk = 0; kk < 2; ++kk)
            #pragma unroll
            for (int j = 0; j < 4; ++j)
                bb[kk][j] = *(const bf16x8*)(B + (size_t)(n0 + wn + j*16 + l15) * K
                                             + k0 + kk*32 + quad*8);
    };

    // compute one tile: A from LDS buf, B from registers
    auto compute_tile = [&](int buf, bf16x8 (&bb)[2][4]) {
        #pragma unroll
        for (int kk = 0; kk < 2; ++kk) {
            bf16x8 a[4];
            #pragma unroll
            for (int i = 0; i < 4; ++i) {
                int m = wm + i*16 + l15;
                int ca = (kk*4 + quad) ^ (m & 7);
                a[i] = *(const bf16x8*)&As[buf][m*64 + ca*8];
            }
            __builtin_amdgcn_s_setprio(1);
            #pragma unroll
            for (int i = 0; i < 4; ++i)
                #pragma unroll
                for (int j = 0; j < 4; ++j)
                    acc[i][j] = __builtin_amdgcn_mfma_f32_16x16x32_bf16(a[i], bb[kk][j], acc[i][j], 0, 0, 0);
            __builtin_amdgcn_s_setprio(0);
        }
    };

    const int NT = K / 64;                 // 12 (even) for K=768
    bf16x8 b0[2][4], b1[2][4];
    stage(0, 0);
    loadB(b0, 0);
    __syncthreads();                       // drains prologue asyncs + b0

    for (int t = 0; t < NT; t += 2) {
        // tile t (buf 0, b0); prefetch t+1 (buf 1, b1)
        if (t + 1 < NT) { stage(1, t + 1); loadB(b1, t + 1); }
        compute_tile(0, b0);
        __syncthreads();
        // tile t+1 (buf 1, b1); prefetch t+2 (buf 0, b0)
        if (t + 2 < NT) { stage(0, t + 2); loadB(b0, t + 2); }
        compute_tile(1, b1);
        __syncthreads();
    }

    if (VFRAG && n0 >= 2*CDIM) {
        // ---- V tile: write PV 16x16x32 B-fragments straight to Vt ----
        #pragma unroll
        for (int i = 0; i < 4; ++i) {
            int gm = m0 + wm + i*16 + quad*4;      // seq base for r=0..3
            int bb = gm >> 11;                     // batch
            int kt = (gm & 2047) >> 6;             // 64-key tile
            int t  = i >> 1;                       // 32-key block within tile
            int wj = (i & 1) * 4;                  // word offset in fragment
            #pragma unroll
            for (int j = 0; j < 4; ++j) {
                int gn = n0 + wn + j*16 + l15;
                float bv = bias[gn];
                int d = gn - 2*CDIM;
                int h = d >> 6, jd = (d & 63) >> 4;  // jd == j
                int bh = bb * NHEADS + h;
                u32 p0 = prnd(acc[i][j][0] + bv);
                u32 p1 = prnd(acc[i][j][1] + bv);
                u32 p2 = prnd(acc[i][j][2] + bv);
                u32 p3 = prnd(acc[i][j][3] + bv);
                uint2 st;
                st.x = __builtin_amdgcn_perm(p1, p0, 0x07060302u);
                st.y = __builtin_amdgcn_perm(p3, p2, 0x07060302u);
                *(uint2*)(Vt + ((size_t)(bh*32 + kt))*VTILE
                             + (size_t)((t*4 + jd)*64 + lane)*8 + wj) = st;
            }
        }
    } else {
        #pragma unroll
        for (int i = 0; i < 4; ++i) {
            #pragma unroll
            for (int j = 0; j < 4; ++j) {
                int gn = n0 + wn + j*16 + l15;
                float bv = bias[gn];
                float sc = (gn < qn) ? qscale : 1.0f;
                #pragma unroll
                for (int r = 0; r < 4; ++r) {
                    int gm = m0 + wm + i*16 + quad*4 + r;
                    float v = (acc[i][j][r] + bv) * sc;
                    if (OUTF32) ((float*)Y)[(size_t)gm * N + gn] = v;
                    else        ((u16*)Y)[(size_t)gm * N + gn] = f2b(v);
                }
            }
        }
    }
}

// ---------------------------------------------------------------------------
// MFMA flash attention, PAIRED K-TILES (round-12 version, total-best 208.0).
// 83% issue-sum (MFMA 38 + VALU 45) = near this structure's bound; T15 and
// pair-barrier variants both failed to beat it — attn is frozen.
// S^T = K.Q^T, exp2 in-register, P packed prnd+v_perm into bf16x8 fragments
// matching the Vt layout -> full-rate 16x16x32 PV. Zero-C first S-half.
// V split: idx-0 half LDS, idx-1 direct-global. setprio (T5), XCD swz (T1).
// ---------------------------------------------------------------------------
__global__ __launch_bounds__(256, 3)
void attn_mfma(const u16* __restrict__ QK, const u16* __restrict__ Vt,
               u16* __restrict__ Oa)
{
    __shared__ __align__(16) u16 Ks[2][2][64*64];   // [pair][tile-in-pair]
    __shared__ __align__(16) u16 Vls[2][2][2048];

    const int tid = threadIdx.x;
    const int wid = tid >> 6, lane = tid & 63;
    const int l15 = lane & 15, quad = lane >> 4;
    const int fid = blockIdx.y * gridDim.x + blockIdx.x;
    const int swz = (fid & 7) * 96 + (fid >> 3);
    const int qt = swz & 15, bh = swz >> 4;
    const int b = bh / NHEADS, h = bh % NHEADS;

    const u16* Qg  = QK + ((size_t)(b*SEQ + qt*QROWS)) * NQKV + h*HDIM;
    const u16* Kg0 = QK + ((size_t)(b*SEQ)) * NQKV + CDIM + h*HDIM;
    const u16* Vg  = Vt + (size_t)bh * 32 * VTILE;

    auto stage2 = [&](int wp, int kt) {
        #pragma unroll
        for (int u = 0; u < 2; ++u) {
            #pragma unroll
            for (int r = 0; r < 2; ++r) {
                int li = r*256 + tid, row = li >> 3, c = li & 7, gc = c ^ (row & 7);
                ASYNC16(Kg0 + (size_t)((kt+u)*64 + row) * NQKV + gc*8, &Ks[wp][u][li*8]);
            }
            ASYNC16(Vg + (size_t)(kt+u) * VTILE + tid*8, &Vls[wp][u][tid*8]);
        }
    };

    stage2(0, 0);

    bf16x8 qf[2][2];
    #pragma unroll
    for (int mb = 0; mb < 2; ++mb)
        #pragma unroll
        for (int kk = 0; kk < 2; ++kk)
            qf[mb][kk] = *(const bf16x8*)(Qg + (size_t)(wid*32 + mb*16 + l15) * NQKV + kk*32 + quad*8);

    const bf16x8 ONES8 = { (short)0x3F80, (short)0x3F80, (short)0x3F80, (short)0x3F80,
                           (short)0x3F80, (short)0x3F80, (short)0x3F80, (short)0x3F80 };
    const f32x4 ZERO4 = { 0.f, 0.f, 0.f, 0.f };

    f32x4 o[2][4];
    #pragma unroll
    for (int mb = 0; mb < 2; ++mb)
        #pragma unroll
        for (int j = 0; j < 4; ++j)
            #pragma unroll
            for (int r = 0; r < 4; ++r) o[mb][j][r] = 0.f;
    f32x4 ll[2];
    #pragma unroll
    for (int mb = 0; mb < 2; ++mb)
        #pragma unroll
        for (int r = 0; r < 4; ++r) ll[mb][r] = 0.f;

    __syncthreads();

    auto body = [&](int kt, int rp, int u) {
        bf16x8 vf[2][4];
        #pragma unroll
        for (int jd = 0; jd < 4; ++jd) {
            vf[0][jd] = *(const bf16x8*)&Vls[rp][u][(size_t)(jd*64 + lane)*8];
            vf[1][jd] = *(const bf16x8*)(Vg + (size_t)kt * VTILE
                                         + (size_t)((4 + jd)*64 + lane)*8);
        }

        f32x4 s[2][4];
        __builtin_amdgcn_s_setprio(1);
        #pragma unroll
        for (int j = 0; j < 4; ++j) {
            int kr = j*16 + l15;
            int ck = quad ^ (kr & 7);
            bf16x8 ak = *(const bf16x8*)&Ks[rp][u][kr*64 + ck*8];
            #pragma unroll
            for (int mb = 0; mb < 2; ++mb)
                s[mb][j] = __builtin_amdgcn_mfma_f32_16x16x32_bf16(ak, qf[mb][0], ZERO4, 0, 0, 0);
        }
        #pragma unroll
        for (int j = 0; j < 4; ++j) {
            int kr = j*16 + l15;
            int ck = (4 + quad) ^ (kr & 7);
            bf16x8 ak = *(const bf16x8*)&Ks[rp][u][kr*64 + ck*8];
            #pragma unroll
            for (int mb = 0; mb < 2; ++mb)
                s[mb][j] = __builtin_amdgcn_mfma_f32_16x16x32_bf16(ak, qf[mb][1], s[mb][j], 0, 0, 0);
        }
        __builtin_amdgcn_s_setprio(0);

        bf16x8 pf[2][2];
        #pragma unroll
        for (int mb = 0; mb < 2; ++mb)
            #pragma unroll
            for (int t = 0; t < 2; ++t) {
                u32 a0 = prnd(__builtin_amdgcn_exp2f(s[mb][2*t][0]));
                u32 a1 = prnd(__builtin_amdgcn_exp2f(s[mb][2*t][1]));
                u32 a2 = prnd(__builtin_amdgcn_exp2f(s[mb][2*t][2]));
                u32 a3 = prnd(__builtin_amdgcn_exp2f(s[mb][2*t][3]));
                u32 b0 = prnd(__builtin_amdgcn_exp2f(s[mb][2*t+1][0]));
                u32 b1 = prnd(__builtin_amdgcn_exp2f(s[mb][2*t+1][1]));
                u32 b2 = prnd(__builtin_amdgcn_exp2f(s[mb][2*t+1][2]));
                u32 b3 = prnd(__builtin_amdgcn_exp2f(s[mb][2*t+1][3]));
                union { uint4 u; bf16x8 v; } cst;
                cst.u.x = __builtin_amdgcn_perm(a1, a0, 0x07060302u);
                cst.u.y = __builtin_amdgcn_perm(a3, a2, 0x07060302u);
                cst.u.z = __builtin_amdgcn_perm(b1, b0, 0x07060302u);
                cst.u.w = __builtin_amdgcn_perm(b3, b2, 0x07060302u);
                pf[mb][t] = cst.v;
            }

        __builtin_amdgcn_s_setprio(1);
        #pragma unroll
        for (int t = 0; t < 2; ++t) {
            #pragma unroll
            for (int jd = 0; jd < 4; ++jd) {
                #pragma unroll
                for (int mb = 0; mb < 2; ++mb)
                    o[mb][jd] = __builtin_amdgcn_mfma_f32_16x16x32_bf16(pf[mb][t], vf[t][jd], o[mb][jd], 0, 0, 0);
            }
            #pragma unroll
            for (int mb = 0; mb < 2; ++mb)
                ll[mb] = __builtin_amdgcn_mfma_f32_16x16x32_bf16(pf[mb][t], ONES8, ll[mb], 0, 0, 0);
        }
        __builtin_amdgcn_s_setprio(0);
    };

    for (int s = 0; s < 16; ++s) {
        const int rp = s & 1, wp = rp ^ 1;
        if (s < 15) stage2(wp, 2*s + 2);
        body(2*s,     rp, 0);
        body(2*s + 1, rp, 1);
        __syncthreads();
    }

    u16* Og = Oa + ((size_t)(b*SEQ + qt*QROWS)) * CDIM + h*HDIM;
    #pragma unroll
    for (int mb = 0; mb < 2; ++mb) {
        #pragma unroll
        for (int r = 0; r < 4; ++r) {
            float inv = 1.f / ll[mb][r];
            int row = wid*32 + mb*16 + quad*4 + r;
            #pragma unroll
            for (int jd = 0; jd < 4; ++jd)
                Og[(size_t)row * CDIM + jd*16 + l15] = f2b(o[mb][jd][r] * inv);
        }
    }
}

// ---------------------------------------------------------------------------
extern "C" void kernel_launch(void* const* d_in, const int* in_sizes, int n_in,
                              void* d_out, int out_size, void* d_ws, size_t ws_size,
                              hipStream_t stream)
{
    const float* x  = (const float*)d_in[0];
    const float* Wq = (const float*)d_in[1];
    const float* bq = (const float*)d_in[2];
    const float* Wk = (const float*)d_in[3];
    const float* bk = (const float*)d_in[4];
    const float* Wv = (const float*)d_in[5];
    const float* bv = (const float*)d_in[6];
    const float* Wo = (const float*)d_in[7];
    const float* bo = (const float*)d_in[8];

    unsigned char* ws = (unsigned char*)d_ws;
    u16* xb   = (u16*)ws;  ws += (size_t)MTOT * CDIM * 2;
    u16* wqkv = (u16*)ws;  ws += (size_t)NQKV * CDIM * 2;
    u16* wob  = (u16*)ws;  ws += (size_t)CDIM * CDIM * 2;
    float* bcat = (float*)ws; ws += (size_t)NQKV * 4;
    u16* qkv  = (u16*)ws;  ws += (size_t)MTOT * NQKV * 2;
    u16* vt   = (u16*)ws;  ws += (size_t)BATCH*NHEADS*32*VTILE * 2;
    u16* ao   = (u16*)ws;

    prep_kern<<<XBLK + 4*WBLK + 9, 256, 0, stream>>>(x, Wq, Wk, Wv, Wo, bq, bk, bv,
                                                     xb, wqkv, wob, bcat);

    // q pre-scaled by log2(e)/sqrt(HDIM) so softmax is a bare exp2
    gemm_bf16<0,1><<<dim3(NQKV/128, MTOT/128), 256, 0, stream>>>(xb, wqkv, bcat, qkv, vt, NQKV, CDIM, CDIM, 0.18033688f);
    attn_mfma<<<dim3(SEQ/QROWS, BATCH*NHEADS), 256, 0, stream>>>(qkv, vt, ao);
    gemm_bf16<1,0><<<dim3(CDIM/128, MTOT/128), 256, 0, stream>>>(ao, wob, bo, (float*)d_out, nullptr, CDIM, CDIM, 0, 1.0f);
}

// Round 16
// 211.284 us; speedup vs baseline: 1.2157x; 1.1908x over previous
//
#include <hip/hip_runtime.h>
#include <math.h>

#define CDIM 768
#define NHEADS 12
#define HDIM 64
#define BATCH 4
#define SEQ 2048
#define MTOT (BATCH*SEQ)     // 8192
#define NQKV (3*CDIM)        // 2304
#define QROWS 128            // Q rows per attention block
#define VTILE 4096           // u16 elements per fragmented V tile (2 blk * 4 jd * 64 lane * 8)

typedef __attribute__((ext_vector_type(8))) short bf16x8;
typedef __attribute__((ext_vector_type(4))) float f32x4;
typedef unsigned short u16;
typedef unsigned int u32;

// async global->LDS, 16B per lane. LDS dest must be wave-uniform base + lane*16
// (global source address is per-lane free-form).
#define ASYNC16(gsrc, ldst) \
  __builtin_amdgcn_global_load_lds((const __attribute__((address_space(1))) void*)(gsrc), \
                                   (__attribute__((address_space(3))) void*)(ldst), 16, 0, 0)

// RNE fp32->bf16 (finite inputs only)
__device__ inline u16 f2b(float x) {
    unsigned int u = __float_as_uint(x);
    return (u16)((u + 0x7fffu + ((u >> 16) & 1u)) >> 16);
}
// rounding-biased uint for pack: hi16(u+0x8000) = round-half-up-in-magnitude bf16
__device__ inline u32 prnd(float x) { return __float_as_uint(x) + 0x8000u; }

// ---------------------------------------------------------------------------
// Fused prologue: x cast (6144 blocks) + 4 weight casts (4*576) + bias concat (9)
// ---------------------------------------------------------------------------
#define XBLK (MTOT*CDIM/1024)        // 6144
#define WBLK (CDIM*CDIM/1024)        // 576
__global__ __launch_bounds__(256)
void prep_kern(const float* __restrict__ x,
               const float* __restrict__ Wq, const float* __restrict__ Wk,
               const float* __restrict__ Wv, const float* __restrict__ Wo,
               const float* __restrict__ bq, const float* __restrict__ bk,
               const float* __restrict__ bv,
               u16* __restrict__ xb, u16* __restrict__ wqkv, u16* __restrict__ wob,
               float* __restrict__ bcat)
{
    int bx = blockIdx.x, tid = threadIdx.x;
    if (bx < XBLK) {
        int i = (bx * 256 + tid) * 4;
        float4 v = *(const float4*)(x + i);
        ushort4 o;
        o.x = f2b(v.x); o.y = f2b(v.y); o.z = f2b(v.z); o.w = f2b(v.w);
        *(ushort4*)(xb + i) = o;
    } else if (bx < XBLK + 4*WBLK) {
        int z = (bx - XBLK) / WBLK;
        int blk = (bx - XBLK) % WBLK;
        const float* src = (z == 0) ? Wq : (z == 1) ? Wk : (z == 2) ? Wv : Wo;
        u16* dst = (z == 3) ? wob : wqkv + (size_t)z * CDIM * CDIM;
        int i = (blk * 256 + tid) * 4;
        float4 v = *(const float4*)(src + i);
        ushort4 o;
        o.x = f2b(v.x); o.y = f2b(v.y); o.z = f2b(v.z); o.w = f2b(v.w);
        *(ushort4*)(dst + i) = o;
    } else {
        int i = (bx - XBLK - 4*WBLK) * 256 + tid;
        if (i < CDIM) bcat[i] = bq[i];
        else if (i < 2*CDIM) bcat[i] = bk[i - CDIM];
        else if (i < 3*CDIM) bcat[i] = bv[i - 2*CDIM];
    }
}

// ---------------------------------------------------------------------------
// bf16 GEMM: Y[m,n] = (sum_k A[m,k]*B[n,k] + bias[n]) * (n<qn ? qscale : 1)
// 128x128 tile, BK=64, 4 waves (2x2 of 64x64), 16x16x32 MFMA, XOR-swizzled
// global_load_lds staging, DOUBLE-BUFFERED (T3 minimum-2-phase).
// FINAL design-space verdict (rounds 5/6/9/10/13/14/15): single-buf 65.9us;
// BK=64 dbuf ~58us (BEST); BK=32 tri-buf+counted-vmcnt 65.3 (T4 null on
// 2-phase); BK=32 dbuf +14us (barrier doubling); 256^2 8-phase 76us (1
// block/CU occupancy collapse); B-direct 87us (exposed L2 latency);
// B-reg-prefetch 79us (same TA/L1 fill path, no win). The ~17% MfmaUtil is
// a fill-path bound shared by all operand placements at this geometry —
// both-operands-LDS BK=64 dbuf is the measured optimum.
// XCD-aware block swizzle (T1): FETCH 70.6->47.8MB, L2-local panels.
// VFRAG=1: tiles with n0>=1536 (the V columns of the QKV GEMM) are written
// as pre-packed PV fragments into Vt instead of rows into Y.
// Fragment layout (matched to 16x16x32 PV MFMA, semantic k within a 32-key
// block: k(quad,j) = j<4 ? 4*quad+j : 16+4*quad+(j-4)):
//   epilogue element (i,j',r): seq s64 = i*16+quad*4+r -> t=i>>1,
//   word wj = 4*(i&1)+r, fragment lane = quad*16 + l15, jd = j'.
//   Vt[(bh*32+kt)*VTILE + ((t*4+jd)*64 + lane)*8 + 4*(i&1) + r]
// ---------------------------------------------------------------------------
template<int OUTF32, int VFRAG>
__global__ __launch_bounds__(256)
void gemm_bf16(const u16* __restrict__ A, const u16* __restrict__ B,
               const float* __restrict__ bias, void* __restrict__ Y,
               u16* __restrict__ Vt,
               int N, int K, int qn, float qscale)
{
    __shared__ __align__(16) u16 As[2][128*64];
    __shared__ __align__(16) u16 Bs[2][128*64];
    const int tid = threadIdx.x;
    // ---- XCD swizzle: nwg % 8 == 0 for all launches (1152 / 384) ----
    const int nwg = gridDim.x * gridDim.y;
    const int fid = blockIdx.y * gridDim.x + blockIdx.x;
    const int swz = (fid & 7) * (nwg >> 3) + (fid >> 3);
    const int m0 = (swz / gridDim.x) * 128, n0 = (swz % gridDim.x) * 128;
    const int wid = tid >> 6, lane = tid & 63;
    const int wm = (wid & 1) * 64, wn = (wid >> 1) * 64;
    const int l15 = lane & 15, quad = lane >> 4;

    f32x4 acc[4][4];
    #pragma unroll
    for (int i = 0; i < 4; ++i)
        #pragma unroll
        for (int j = 0; j < 4; ++j)
            #pragma unroll
            for (int r = 0; r < 4; ++r) acc[i][j][r] = 0.f;

    auto stage = [&](int buf, int t) {
        int k0 = t * 64;
        #pragma unroll
        for (int r = 0; r < 4; ++r) {
            int li = r*256 + tid;
            int row = li >> 3, c = li & 7;
            int gc = c ^ (row & 7);
            ASYNC16(A + (size_t)(m0 + row) * K + k0 + gc*8, &As[buf][li*8]);
            ASYNC16(B + (size_t)(n0 + row) * K + k0 + gc*8, &Bs[buf][li*8]);
        }
    };

    const int NT = K / 64;
    stage(0, 0);
    __syncthreads();                       // drains prologue asyncs

    for (int t = 0; t < NT; ++t) {
        const int bufc = t & 1;
        if (t + 1 < NT) stage(bufc ^ 1, t + 1);   // overlap with MFMA below
        #pragma unroll
        for (int kk = 0; kk < 2; ++kk) {
            bf16x8 a[4], b[4];
            #pragma unroll
            for (int i = 0; i < 4; ++i) {
                int m = wm + i*16 + l15;
                int ca = (kk*4 + quad) ^ (m & 7);
                a[i] = *(const bf16x8*)&As[bufc][m*64 + ca*8];
                int n = wn + i*16 + l15;
                int cbx = (kk*4 + quad) ^ (n & 7);
                b[i] = *(const bf16x8*)&Bs[bufc][n*64 + cbx*8];
            }
            #pragma unroll
            for (int i = 0; i < 4; ++i)
                #pragma unroll
                for (int j = 0; j < 4; ++j)
                    acc[i][j] = __builtin_amdgcn_mfma_f32_16x16x32_bf16(a[i], b[j], acc[i][j], 0, 0, 0);
        }
        __syncthreads();   // drains next-tile asyncs; protects buffer reuse
    }

    if (VFRAG && n0 >= 2*CDIM) {
        // ---- V tile: write PV 16x16x32 B-fragments straight to Vt ----
        #pragma unroll
        for (int i = 0; i < 4; ++i) {
            int gm = m0 + wm + i*16 + quad*4;      // seq base for r=0..3
            int bb = gm >> 11;                     // batch
            int kt = (gm & 2047) >> 6;             // 64-key tile
            int t  = i >> 1;                       // 32-key block within tile
            int wj = (i & 1) * 4;                  // word offset in fragment
            #pragma unroll
            for (int j = 0; j < 4; ++j) {
                int gn = n0 + wn + j*16 + l15;
                float bv = bias[gn];
                int d = gn - 2*CDIM;
                int h = d >> 6, jd = (d & 63) >> 4;  // jd == j
                int bh = bb * NHEADS + h;
                u32 p0 = prnd(acc[i][j][0] + bv);
                u32 p1 = prnd(acc[i][j][1] + bv);
                u32 p2 = prnd(acc[i][j][2] + bv);
                u32 p3 = prnd(acc[i][j][3] + bv);
                uint2 st;
                st.x = __builtin_amdgcn_perm(p1, p0, 0x07060302u);
                st.y = __builtin_amdgcn_perm(p3, p2, 0x07060302u);
                *(uint2*)(Vt + ((size_t)(bh*32 + kt))*VTILE
                             + (size_t)((t*4 + jd)*64 + lane)*8 + wj) = st;
            }
        }
    } else {
        #pragma unroll
        for (int i = 0; i < 4; ++i) {
            #pragma unroll
            for (int j = 0; j < 4; ++j) {
                int gn = n0 + wn + j*16 + l15;
                float bv = bias[gn];
                float sc = (gn < qn) ? qscale : 1.0f;
                #pragma unroll
                for (int r = 0; r < 4; ++r) {
                    int gm = m0 + wm + i*16 + quad*4 + r;
                    float v = (acc[i][j][r] + bv) * sc;
                    if (OUTF32) ((float*)Y)[(size_t)gm * N + gn] = v;
                    else        ((u16*)Y)[(size_t)gm * N + gn] = f2b(v);
                }
            }
        }
    }
}

// ---------------------------------------------------------------------------
// MFMA flash attention, PAIRED K-TILES (round-12 version, total-best 208.0).
// 83% issue-sum (MFMA 38 + VALU 45) = near this structure's bound; T15 and
// pair-barrier variants both failed to beat it — attn is frozen.
// S^T = K.Q^T, exp2 in-register, P packed prnd+v_perm into bf16x8 fragments
// matching the Vt layout -> full-rate 16x16x32 PV. Zero-C first S-half.
// V split: idx-0 half LDS, idx-1 direct-global. setprio (T5), XCD swz (T1).
// ---------------------------------------------------------------------------
__global__ __launch_bounds__(256, 3)
void attn_mfma(const u16* __restrict__ QK, const u16* __restrict__ Vt,
               u16* __restrict__ Oa)
{
    __shared__ __align__(16) u16 Ks[2][2][64*64];   // [pair][tile-in-pair]
    __shared__ __align__(16) u16 Vls[2][2][2048];

    const int tid = threadIdx.x;
    const int wid = tid >> 6, lane = tid & 63;
    const int l15 = lane & 15, quad = lane >> 4;
    const int fid = blockIdx.y * gridDim.x + blockIdx.x;
    const int swz = (fid & 7) * 96 + (fid >> 3);
    const int qt = swz & 15, bh = swz >> 4;
    const int b = bh / NHEADS, h = bh % NHEADS;

    const u16* Qg  = QK + ((size_t)(b*SEQ + qt*QROWS)) * NQKV + h*HDIM;
    const u16* Kg0 = QK + ((size_t)(b*SEQ)) * NQKV + CDIM + h*HDIM;
    const u16* Vg  = Vt + (size_t)bh * 32 * VTILE;

    auto stage2 = [&](int wp, int kt) {
        #pragma unroll
        for (int u = 0; u < 2; ++u) {
            #pragma unroll
            for (int r = 0; r < 2; ++r) {
                int li = r*256 + tid, row = li >> 3, c = li & 7, gc = c ^ (row & 7);
                ASYNC16(Kg0 + (size_t)((kt+u)*64 + row) * NQKV + gc*8, &Ks[wp][u][li*8]);
            }
            ASYNC16(Vg + (size_t)(kt+u) * VTILE + tid*8, &Vls[wp][u][tid*8]);
        }
    };

    stage2(0, 0);

    bf16x8 qf[2][2];
    #pragma unroll
    for (int mb = 0; mb < 2; ++mb)
        #pragma unroll
        for (int kk = 0; kk < 2; ++kk)
            qf[mb][kk] = *(const bf16x8*)(Qg + (size_t)(wid*32 + mb*16 + l15) * NQKV + kk*32 + quad*8);

    const bf16x8 ONES8 = { (short)0x3F80, (short)0x3F80, (short)0x3F80, (short)0x3F80,
                           (short)0x3F80, (short)0x3F80, (short)0x3F80, (short)0x3F80 };
    const f32x4 ZERO4 = { 0.f, 0.f, 0.f, 0.f };

    f32x4 o[2][4];
    #pragma unroll
    for (int mb = 0; mb < 2; ++mb)
        #pragma unroll
        for (int j = 0; j < 4; ++j)
            #pragma unroll
            for (int r = 0; r < 4; ++r) o[mb][j][r] = 0.f;
    f32x4 ll[2];
    #pragma unroll
    for (int mb = 0; mb < 2; ++mb)
        #pragma unroll
        for (int r = 0; r < 4; ++r) ll[mb][r] = 0.f;

    __syncthreads();

    auto body = [&](int kt, int rp, int u) {
        bf16x8 vf[2][4];
        #pragma unroll
        for (int jd = 0; jd < 4; ++jd) {
            vf[0][jd] = *(const bf16x8*)&Vls[rp][u][(size_t)(jd*64 + lane)*8];
            vf[1][jd] = *(const bf16x8*)(Vg + (size_t)kt * VTILE
                                         + (size_t)((4 + jd)*64 + lane)*8);
        }

        f32x4 s[2][4];
        __builtin_amdgcn_s_setprio(1);
        #pragma unroll
        for (int j = 0; j < 4; ++j) {
            int kr = j*16 + l15;
            int ck = quad ^ (kr & 7);
            bf16x8 ak = *(const bf16x8*)&Ks[rp][u][kr*64 + ck*8];
            #pragma unroll
            for (int mb = 0; mb < 2; ++mb)
                s[mb][j] = __builtin_amdgcn_mfma_f32_16x16x32_bf16(ak, qf[mb][0], ZERO4, 0, 0, 0);
        }
        #pragma unroll
        for (int j = 0; j < 4; ++j) {
            int kr = j*16 + l15;
            int ck = (4 + quad) ^ (kr & 7);
            bf16x8 ak = *(const bf16x8*)&Ks[rp][u][kr*64 + ck*8];
            #pragma unroll
            for (int mb = 0; mb < 2; ++mb)
                s[mb][j] = __builtin_amdgcn_mfma_f32_16x16x32_bf16(ak, qf[mb][1], s[mb][j], 0, 0, 0);
        }
        __builtin_amdgcn_s_setprio(0);

        bf16x8 pf[2][2];
        #pragma unroll
        for (int mb = 0; mb < 2; ++mb)
            #pragma unroll
            for (int t = 0; t < 2; ++t) {
                u32 a0 = prnd(__builtin_amdgcn_exp2f(s[mb][2*t][0]));
                u32 a1 = prnd(__builtin_amdgcn_exp2f(s[mb][2*t][1]));
                u32 a2 = prnd(__builtin_amdgcn_exp2f(s[mb][2*t][2]));
                u32 a3 = prnd(__builtin_amdgcn_exp2f(s[mb][2*t][3]));
                u32 b0 = prnd(__builtin_amdgcn_exp2f(s[mb][2*t+1][0]));
                u32 b1 = prnd(__builtin_amdgcn_exp2f(s[mb][2*t+1][1]));
                u32 b2 = prnd(__builtin_amdgcn_exp2f(s[mb][2*t+1][2]));
                u32 b3 = prnd(__builtin_amdgcn_exp2f(s[mb][2*t+1][3]));
                union { uint4 u; bf16x8 v; } cst;
                cst.u.x = __builtin_amdgcn_perm(a1, a0, 0x07060302u);
                cst.u.y = __builtin_amdgcn_perm(a3, a2, 0x07060302u);
                cst.u.z = __builtin_amdgcn_perm(b1, b0, 0x07060302u);
                cst.u.w = __builtin_amdgcn_perm(b3, b2, 0x07060302u);
                pf[mb][t] = cst.v;
            }

        __builtin_amdgcn_s_setprio(1);
        #pragma unroll
        for (int t = 0; t < 2; ++t) {
            #pragma unroll
            for (int jd = 0; jd < 4; ++jd) {
                #pragma unroll
                for (int mb = 0; mb < 2; ++mb)
                    o[mb][jd] = __builtin_amdgcn_mfma_f32_16x16x32_bf16(pf[mb][t], vf[t][jd], o[mb][jd], 0, 0, 0);
            }
            #pragma unroll
            for (int mb = 0; mb < 2; ++mb)
                ll[mb] = __builtin_amdgcn_mfma_f32_16x16x32_bf16(pf[mb][t], ONES8, ll[mb], 0, 0, 0);
        }
        __builtin_amdgcn_s_setprio(0);
    };

    for (int s = 0; s < 16; ++s) {
        const int rp = s & 1, wp = rp ^ 1;
        if (s < 15) stage2(wp, 2*s + 2);
        body(2*s,     rp, 0);
        body(2*s + 1, rp, 1);
        __syncthreads();
    }

    u16* Og = Oa + ((size_t)(b*SEQ + qt*QROWS)) * CDIM + h*HDIM;
    #pragma unroll
    for (int mb = 0; mb < 2; ++mb) {
        #pragma unroll
        for (int r = 0; r < 4; ++r) {
            float inv = 1.f / ll[mb][r];
            int row = wid*32 + mb*16 + quad*4 + r;
            #pragma unroll
            for (int jd = 0; jd < 4; ++jd)
                Og[(size_t)row * CDIM + jd*16 + l15] = f2b(o[mb][jd][r] * inv);
        }
    }
}

// ---------------------------------------------------------------------------
extern "C" void kernel_launch(void* const* d_in, const int* in_sizes, int n_in,
                              void* d_out, int out_size, void* d_ws, size_t ws_size,
                              hipStream_t stream)
{
    const float* x  = (const float*)d_in[0];
    const float* Wq = (const float*)d_in[1];
    const float* bq = (const float*)d_in[2];
    const float* Wk = (const float*)d_in[3];
    const float* bk = (const float*)d_in[4];
    const float* Wv = (const float*)d_in[5];
    const float* bv = (const float*)d_in[6];
    const float* Wo = (const float*)d_in[7];
    const float* bo = (const float*)d_in[8];

    unsigned char* ws = (unsigned char*)d_ws;
    u16* xb   = (u16*)ws;  ws += (size_t)MTOT * CDIM * 2;
    u16* wqkv = (u16*)ws;  ws += (size_t)NQKV * CDIM * 2;
    u16* wob  = (u16*)ws;  ws += (size_t)CDIM * CDIM * 2;
    float* bcat = (float*)ws; ws += (size_t)NQKV * 4;
    u16* qkv  = (u16*)ws;  ws += (size_t)MTOT * NQKV * 2;
    u16* vt   = (u16*)ws;  ws += (size_t)BATCH*NHEADS*32*VTILE * 2;
    u16* ao   = (u16*)ws;

    prep_kern<<<XBLK + 4*WBLK + 9, 256, 0, stream>>>(x, Wq, Wk, Wv, Wo, bq, bk, bv,
                                                     xb, wqkv, wob, bcat);

    // q pre-scaled by log2(e)/sqrt(HDIM) so softmax is a bare exp2
    gemm_bf16<0,1><<<dim3(NQKV/128, MTOT/128), 256, 0, stream>>>(xb, wqkv, bcat, qkv, vt, NQKV, CDIM, CDIM, 0.18033688f);
    attn_mfma<<<dim3(SEQ/QROWS, BATCH*NHEADS), 256, 0, stream>>>(qkv, vt, ao);
    gemm_bf16<1,0><<<dim3(CDIM/128, MTOT/128), 256, 0, stream>>>(ao, wob, bo, (float*)d_out, nullptr, CDIM, CDIM, 0, 1.0f);
}

// Round 17
// 204.477 us; speedup vs baseline: 1.2562x; 1.0333x over previous
//
#include <hip/hip_runtime.h>
#include <math.h>

#define CDIM 768
#define NHEADS 12
#define HDIM 64
#define BATCH 4
#define SEQ 2048
#define MTOT (BATCH*SEQ)     // 8192
#define NQKV (3*CDIM)        // 2304
#define QROWS 128            // Q rows per attention block
#define VTILE 4096           // u16 elements per fragmented V tile (2 blk * 4 jd * 64 lane * 8)

typedef __attribute__((ext_vector_type(8))) short bf16x8;
typedef __attribute__((ext_vector_type(4))) float f32x4;
typedef unsigned short u16;
typedef unsigned int u32;

// async global->LDS, 16B per lane. LDS dest must be wave-uniform base + lane*16
// (global source address is per-lane free-form).
#define ASYNC16(gsrc, ldst) \
  __builtin_amdgcn_global_load_lds((const __attribute__((address_space(1))) void*)(gsrc), \
                                   (__attribute__((address_space(3))) void*)(ldst), 16, 0, 0)

// RNE fp32->bf16 (finite inputs only)
__device__ inline u16 f2b(float x) {
    unsigned int u = __float_as_uint(x);
    return (u16)((u + 0x7fffu + ((u >> 16) & 1u)) >> 16);
}
// rounding-biased uint for pack: hi16(u+0x8000) = round-half-up-in-magnitude bf16
__device__ inline u32 prnd(float x) { return __float_as_uint(x) + 0x8000u; }

// ---------------------------------------------------------------------------
// Fused prologue: x cast (6144 blocks) + 4 weight casts (4*576) + bias concat (9)
// ---------------------------------------------------------------------------
#define XBLK (MTOT*CDIM/1024)        // 6144
#define WBLK (CDIM*CDIM/1024)        // 576
__global__ __launch_bounds__(256)
void prep_kern(const float* __restrict__ x,
               const float* __restrict__ Wq, const float* __restrict__ Wk,
               const float* __restrict__ Wv, const float* __restrict__ Wo,
               const float* __restrict__ bq, const float* __restrict__ bk,
               const float* __restrict__ bv,
               u16* __restrict__ xb, u16* __restrict__ wqkv, u16* __restrict__ wob,
               float* __restrict__ bcat)
{
    int bx = blockIdx.x, tid = threadIdx.x;
    if (bx < XBLK) {
        int i = (bx * 256 + tid) * 4;
        float4 v = *(const float4*)(x + i);
        ushort4 o;
        o.x = f2b(v.x); o.y = f2b(v.y); o.z = f2b(v.z); o.w = f2b(v.w);
        *(ushort4*)(xb + i) = o;
    } else if (bx < XBLK + 4*WBLK) {
        int z = (bx - XBLK) / WBLK;
        int blk = (bx - XBLK) % WBLK;
        const float* src = (z == 0) ? Wq : (z == 1) ? Wk : (z == 2) ? Wv : Wo;
        u16* dst = (z == 3) ? wob : wqkv + (size_t)z * CDIM * CDIM;
        int i = (blk * 256 + tid) * 4;
        float4 v = *(const float4*)(src + i);
        ushort4 o;
        o.x = f2b(v.x); o.y = f2b(v.y); o.z = f2b(v.z); o.w = f2b(v.w);
        *(ushort4*)(dst + i) = o;
    } else {
        int i = (bx - XBLK - 4*WBLK) * 256 + tid;
        if (i < CDIM) bcat[i] = bq[i];
        else if (i < 2*CDIM) bcat[i] = bk[i - CDIM];
        else if (i < 3*CDIM) bcat[i] = bv[i - 2*CDIM];
    }
}

// ---------------------------------------------------------------------------
// bf16 GEMM: Y[m,n] = (sum_k A[m,k]*B[n,k] + bias[n]) * (n<qn ? qscale : 1)
// 128x192 tile (TM=128, TN=192), BK=64, 4 waves (2x2 of 64x96), 16x16x32
// MFMA, XOR-swizzled global_load_lds staging, DOUBLE-BUFFERED.
// WHY 128x192: per-output-FLOP fill traffic = (1/TM + 1/TN) B/FLOP;
// 128x192 = 0.0130 vs 128^2's 0.0156 (-17%) and 1.5x MFMA-per-barrier,
// WITHOUT the occupancy collapse that killed 256^2 (LDS 2x(16+24)=80KB ->
// still 2 blocks/CU, same as 64KB config) and with the proven 1-barrier/
// step sync structure untouched. Design-space verdict so far (r5-r15):
// BK=64 dbuf both-LDS is best of {single-buf, BK32 tri/dbuf, 256^2,
// B-direct, B-reg-prefetch}; this round tests the last safe geometry cell.
// XCD swizzle (T1): grids 768 / 256 blocks, %8==0 -> bijective.
// VFRAG=1: V-column tiles (n0>=1536; 1536 = 8*192 exactly, so V tiles are
// pure) written as pre-packed PV fragments into Vt:
//   Vt[(bh*32+kt)*VTILE + ((t*4+jd)*64 + lane)*8 + 4*(i&1) + r],
//   t = i>>1, wj = (i&1)*4 (wm/m0 granularity unchanged), jd = (d&63)>>4.
// ---------------------------------------------------------------------------
template<int OUTF32, int VFRAG>
__global__ __launch_bounds__(256)
void gemm_bf16(const u16* __restrict__ A, const u16* __restrict__ B,
               const float* __restrict__ bias, void* __restrict__ Y,
               u16* __restrict__ Vt,
               int N, int K, int qn, float qscale)
{
    __shared__ __align__(16) u16 As[2][128*64];
    __shared__ __align__(16) u16 Bs[2][192*64];
    const int tid = threadIdx.x;
    // ---- XCD swizzle: nwg % 8 == 0 for all launches (768 / 256) ----
    const int nwg = gridDim.x * gridDim.y;
    const int fid = blockIdx.y * gridDim.x + blockIdx.x;
    const int swz = (fid & 7) * (nwg >> 3) + (fid >> 3);
    const int m0 = (swz / gridDim.x) * 128, n0 = (swz % gridDim.x) * 192;
    const int wid = tid >> 6, lane = tid & 63;
    const int wm = (wid & 1) * 64, wn = (wid >> 1) * 96;
    const int l15 = lane & 15, quad = lane >> 4;

    f32x4 acc[4][6];
    #pragma unroll
    for (int i = 0; i < 4; ++i)
        #pragma unroll
        for (int j = 0; j < 6; ++j)
            #pragma unroll
            for (int r = 0; r < 4; ++r) acc[i][j][r] = 0.f;

    auto stage = [&](int buf, int t) {
        int k0 = t * 64;
        #pragma unroll
        for (int r = 0; r < 4; ++r) {
            int li = r*256 + tid;
            int row = li >> 3, c = li & 7;
            int gc = c ^ (row & 7);
            ASYNC16(A + (size_t)(m0 + row) * K + k0 + gc*8, &As[buf][li*8]);
        }
        #pragma unroll
        for (int r = 0; r < 6; ++r) {
            int li = r*256 + tid;
            int row = li >> 3, c = li & 7;
            int gc = c ^ (row & 7);
            ASYNC16(B + (size_t)(n0 + row) * K + k0 + gc*8, &Bs[buf][li*8]);
        }
    };

    const int NT = K / 64;
    stage(0, 0);
    __syncthreads();                       // drains prologue asyncs

    for (int t = 0; t < NT; ++t) {
        const int bufc = t & 1;
        if (t + 1 < NT) stage(bufc ^ 1, t + 1);   // overlap with MFMA below
        #pragma unroll
        for (int kk = 0; kk < 2; ++kk) {
            bf16x8 a[4], b[6];
            #pragma unroll
            for (int i = 0; i < 4; ++i) {
                int m = wm + i*16 + l15;
                int ca = (kk*4 + quad) ^ (m & 7);
                a[i] = *(const bf16x8*)&As[bufc][m*64 + ca*8];
            }
            #pragma unroll
            for (int j = 0; j < 6; ++j) {
                int n = wn + j*16 + l15;
                int cbx = (kk*4 + quad) ^ (n & 7);
                b[j] = *(const bf16x8*)&Bs[bufc][n*64 + cbx*8];
            }
            #pragma unroll
            for (int i = 0; i < 4; ++i)
                #pragma unroll
                for (int j = 0; j < 6; ++j)
                    acc[i][j] = __builtin_amdgcn_mfma_f32_16x16x32_bf16(a[i], b[j], acc[i][j], 0, 0, 0);
        }
        __syncthreads();   // drains next-tile asyncs; protects buffer reuse
    }

    if (VFRAG && n0 >= 2*CDIM) {
        // ---- V tile: write PV 16x16x32 B-fragments straight to Vt ----
        #pragma unroll
        for (int i = 0; i < 4; ++i) {
            int gm = m0 + wm + i*16 + quad*4;      // seq base for r=0..3
            int bb = gm >> 11;                     // batch
            int kt = (gm & 2047) >> 6;             // 64-key tile
            int t  = i >> 1;                       // 32-key block within tile
            int wj = (i & 1) * 4;                  // word offset in fragment
            #pragma unroll
            for (int j = 0; j < 6; ++j) {
                int gn = n0 + wn + j*16 + l15;
                float bv = bias[gn];
                int d = gn - 2*CDIM;
                int h = d >> 6, jd = (d & 63) >> 4;
                int bh = bb * NHEADS + h;
                u32 p0 = prnd(acc[i][j][0] + bv);
                u32 p1 = prnd(acc[i][j][1] + bv);
                u32 p2 = prnd(acc[i][j][2] + bv);
                u32 p3 = prnd(acc[i][j][3] + bv);
                uint2 st;
                st.x = __builtin_amdgcn_perm(p1, p0, 0x07060302u);
                st.y = __builtin_amdgcn_perm(p3, p2, 0x07060302u);
                *(uint2*)(Vt + ((size_t)(bh*32 + kt))*VTILE
                             + (size_t)((t*4 + jd)*64 + lane)*8 + wj) = st;
            }
        }
    } else {
        #pragma unroll
        for (int i = 0; i < 4; ++i) {
            #pragma unroll
            for (int j = 0; j < 6; ++j) {
                int gn = n0 + wn + j*16 + l15;
                float bv = bias[gn];
                float sc = (gn < qn) ? qscale : 1.0f;
                #pragma unroll
                for (int r = 0; r < 4; ++r) {
                    int gm = m0 + wm + i*16 + quad*4 + r;
                    float v = (acc[i][j][r] + bv) * sc;
                    if (OUTF32) ((float*)Y)[(size_t)gm * N + gn] = v;
                    else        ((u16*)Y)[(size_t)gm * N + gn] = f2b(v);
                }
            }
        }
    }
}

// ---------------------------------------------------------------------------
// MFMA flash attention, PAIRED K-TILES (round-12 version, total-best 208.0).
// 83% issue-sum (MFMA 38 + VALU 45) = near this structure's bound; T15 and
// pair-barrier variants both failed to beat it — attn is frozen.
// S^T = K.Q^T, exp2 in-register, P packed prnd+v_perm into bf16x8 fragments
// matching the Vt layout -> full-rate 16x16x32 PV. Zero-C first S-half.
// V split: idx-0 half LDS, idx-1 direct-global. setprio (T5), XCD swz (T1).
// ---------------------------------------------------------------------------
__global__ __launch_bounds__(256, 3)
void attn_mfma(const u16* __restrict__ QK, const u16* __restrict__ Vt,
               u16* __restrict__ Oa)
{
    __shared__ __align__(16) u16 Ks[2][2][64*64];   // [pair][tile-in-pair]
    __shared__ __align__(16) u16 Vls[2][2][2048];

    const int tid = threadIdx.x;
    const int wid = tid >> 6, lane = tid & 63;
    const int l15 = lane & 15, quad = lane >> 4;
    const int fid = blockIdx.y * gridDim.x + blockIdx.x;
    const int swz = (fid & 7) * 96 + (fid >> 3);
    const int qt = swz & 15, bh = swz >> 4;
    const int b = bh / NHEADS, h = bh % NHEADS;

    const u16* Qg  = QK + ((size_t)(b*SEQ + qt*QROWS)) * NQKV + h*HDIM;
    const u16* Kg0 = QK + ((size_t)(b*SEQ)) * NQKV + CDIM + h*HDIM;
    const u16* Vg  = Vt + (size_t)bh * 32 * VTILE;

    auto stage2 = [&](int wp, int kt) {
        #pragma unroll
        for (int u = 0; u < 2; ++u) {
            #pragma unroll
            for (int r = 0; r < 2; ++r) {
                int li = r*256 + tid, row = li >> 3, c = li & 7, gc = c ^ (row & 7);
                ASYNC16(Kg0 + (size_t)((kt+u)*64 + row) * NQKV + gc*8, &Ks[wp][u][li*8]);
            }
            ASYNC16(Vg + (size_t)(kt+u) * VTILE + tid*8, &Vls[wp][u][tid*8]);
        }
    };

    stage2(0, 0);

    bf16x8 qf[2][2];
    #pragma unroll
    for (int mb = 0; mb < 2; ++mb)
        #pragma unroll
        for (int kk = 0; kk < 2; ++kk)
            qf[mb][kk] = *(const bf16x8*)(Qg + (size_t)(wid*32 + mb*16 + l15) * NQKV + kk*32 + quad*8);

    const bf16x8 ONES8 = { (short)0x3F80, (short)0x3F80, (short)0x3F80, (short)0x3F80,
                           (short)0x3F80, (short)0x3F80, (short)0x3F80, (short)0x3F80 };
    const f32x4 ZERO4 = { 0.f, 0.f, 0.f, 0.f };

    f32x4 o[2][4];
    #pragma unroll
    for (int mb = 0; mb < 2; ++mb)
        #pragma unroll
        for (int j = 0; j < 4; ++j)
            #pragma unroll
            for (int r = 0; r < 4; ++r) o[mb][j][r] = 0.f;
    f32x4 ll[2];
    #pragma unroll
    for (int mb = 0; mb < 2; ++mb)
        #pragma unroll
        for (int r = 0; r < 4; ++r) ll[mb][r] = 0.f;

    __syncthreads();

    auto body = [&](int kt, int rp, int u) {
        bf16x8 vf[2][4];
        #pragma unroll
        for (int jd = 0; jd < 4; ++jd) {
            vf[0][jd] = *(const bf16x8*)&Vls[rp][u][(size_t)(jd*64 + lane)*8];
            vf[1][jd] = *(const bf16x8*)(Vg + (size_t)kt * VTILE
                                         + (size_t)((4 + jd)*64 + lane)*8);
        }

        f32x4 s[2][4];
        __builtin_amdgcn_s_setprio(1);
        #pragma unroll
        for (int j = 0; j < 4; ++j) {
            int kr = j*16 + l15;
            int ck = quad ^ (kr & 7);
            bf16x8 ak = *(const bf16x8*)&Ks[rp][u][kr*64 + ck*8];
            #pragma unroll
            for (int mb = 0; mb < 2; ++mb)
                s[mb][j] = __builtin_amdgcn_mfma_f32_16x16x32_bf16(ak, qf[mb][0], ZERO4, 0, 0, 0);
        }
        #pragma unroll
        for (int j = 0; j < 4; ++j) {
            int kr = j*16 + l15;
            int ck = (4 + quad) ^ (kr & 7);
            bf16x8 ak = *(const bf16x8*)&Ks[rp][u][kr*64 + ck*8];
            #pragma unroll
            for (int mb = 0; mb < 2; ++mb)
                s[mb][j] = __builtin_amdgcn_mfma_f32_16x16x32_bf16(ak, qf[mb][1], s[mb][j], 0, 0, 0);
        }
        __builtin_amdgcn_s_setprio(0);

        bf16x8 pf[2][2];
        #pragma unroll
        for (int mb = 0; mb < 2; ++mb)
            #pragma unroll
            for (int t = 0; t < 2; ++t) {
                u32 a0 = prnd(__builtin_amdgcn_exp2f(s[mb][2*t][0]));
                u32 a1 = prnd(__builtin_amdgcn_exp2f(s[mb][2*t][1]));
                u32 a2 = prnd(__builtin_amdgcn_exp2f(s[mb][2*t][2]));
                u32 a3 = prnd(__builtin_amdgcn_exp2f(s[mb][2*t][3]));
                u32 b0 = prnd(__builtin_amdgcn_exp2f(s[mb][2*t+1][0]));
                u32 b1 = prnd(__builtin_amdgcn_exp2f(s[mb][2*t+1][1]));
                u32 b2 = prnd(__builtin_amdgcn_exp2f(s[mb][2*t+1][2]));
                u32 b3 = prnd(__builtin_amdgcn_exp2f(s[mb][2*t+1][3]));
                union { uint4 u; bf16x8 v; } cst;
                cst.u.x = __builtin_amdgcn_perm(a1, a0, 0x07060302u);
                cst.u.y = __builtin_amdgcn_perm(a3, a2, 0x07060302u);
                cst.u.z = __builtin_amdgcn_perm(b1, b0, 0x07060302u);
                cst.u.w = __builtin_amdgcn_perm(b3, b2, 0x07060302u);
                pf[mb][t] = cst.v;
            }

        __builtin_amdgcn_s_setprio(1);
        #pragma unroll
        for (int t = 0; t < 2; ++t) {
            #pragma unroll
            for (int jd = 0; jd < 4; ++jd) {
                #pragma unroll
                for (int mb = 0; mb < 2; ++mb)
                    o[mb][jd] = __builtin_amdgcn_mfma_f32_16x16x32_bf16(pf[mb][t], vf[t][jd], o[mb][jd], 0, 0, 0);
            }
            #pragma unroll
            for (int mb = 0; mb < 2; ++mb)
                ll[mb] = __builtin_amdgcn_mfma_f32_16x16x32_bf16(pf[mb][t], ONES8, ll[mb], 0, 0, 0);
        }
        __builtin_amdgcn_s_setprio(0);
    };

    for (int s = 0; s < 16; ++s) {
        const int rp = s & 1, wp = rp ^ 1;
        if (s < 15) stage2(wp, 2*s + 2);
        body(2*s,     rp, 0);
        body(2*s + 1, rp, 1);
        __syncthreads();
    }

    u16* Og = Oa + ((size_t)(b*SEQ + qt*QROWS)) * CDIM + h*HDIM;
    #pragma unroll
    for (int mb = 0; mb < 2; ++mb) {
        #pragma unroll
        for (int r = 0; r < 4; ++r) {
            float inv = 1.f / ll[mb][r];
            int row = wid*32 + mb*16 + quad*4 + r;
            #pragma unroll
            for (int jd = 0; jd < 4; ++jd)
                Og[(size_t)row * CDIM + jd*16 + l15] = f2b(o[mb][jd][r] * inv);
        }
    }
}

// ---------------------------------------------------------------------------
extern "C" void kernel_launch(void* const* d_in, const int* in_sizes, int n_in,
                              void* d_out, int out_size, void* d_ws, size_t ws_size,
                              hipStream_t stream)
{
    const float* x  = (const float*)d_in[0];
    const float* Wq = (const float*)d_in[1];
    const float* bq = (const float*)d_in[2];
    const float* Wk = (const float*)d_in[3];
    const float* bk = (const float*)d_in[4];
    const float* Wv = (const float*)d_in[5];
    const float* bv = (const float*)d_in[6];
    const float* Wo = (const float*)d_in[7];
    const float* bo = (const float*)d_in[8];

    unsigned char* ws = (unsigned char*)d_ws;
    u16* xb   = (u16*)ws;  ws += (size_t)MTOT * CDIM * 2;
    u16* wqkv = (u16*)ws;  ws += (size_t)NQKV * CDIM * 2;
    u16* wob  = (u16*)ws;  ws += (size_t)CDIM * CDIM * 2;
    float* bcat = (float*)ws; ws += (size_t)NQKV * 4;
    u16* qkv  = (u16*)ws;  ws += (size_t)MTOT * NQKV * 2;
    u16* vt   = (u16*)ws;  ws += (size_t)BATCH*NHEADS*32*VTILE * 2;
    u16* ao   = (u16*)ws;

    prep_kern<<<XBLK + 4*WBLK + 9, 256, 0, stream>>>(x, Wq, Wk, Wv, Wo, bq, bk, bv,
                                                     xb, wqkv, wob, bcat);

    // q pre-scaled by log2(e)/sqrt(HDIM) so softmax is a bare exp2
    gemm_bf16<0,1><<<dim3(NQKV/192, MTOT/128), 256, 0, stream>>>(xb, wqkv, bcat, qkv, vt, NQKV, CDIM, CDIM, 0.18033688f);
    attn_mfma<<<dim3(SEQ/QROWS, BATCH*NHEADS), 256, 0, stream>>>(qkv, vt, ao);
    gemm_bf16<1,0><<<dim3(CDIM/192, MTOT/128), 256, 0, stream>>>(ao, wob, bo, (float*)d_out, nullptr, CDIM, CDIM, 0, 1.0f);
}